// Round 3
// baseline (1333.675 us; speedup 1.0000x reference)
//
#include <hip/hip_runtime.h>
#include <hip/hip_bf16.h>

#define NN 320
#define CC 128
#define HH 4
#define CHD 32
#define HC 128
#define NP (NN*NN)

typedef __hip_bfloat16 bf16;

__device__ __forceinline__ float bf2f(bf16 b) { return __bfloat162float(b); }

__device__ __forceinline__ unsigned short bfbits(float f) {
    bf16 h = __float2bfloat16(f);
    return *reinterpret_cast<unsigned short*>(&h);
}

__device__ __forceinline__ void store_bf16x4(bf16* p, float a, float b, float c, float d) {
    uint2 u;
    u.x = (unsigned)bfbits(a) | ((unsigned)bfbits(b) << 16);
    u.y = (unsigned)bfbits(c) | ((unsigned)bfbits(d) << 16);
    *reinterpret_cast<uint2*>(p) = u;
}

// unpack a float4-sized chunk holding 8 bf16 into 8 floats
__device__ __forceinline__ void unpack8(float4 r, float* o) {
    const unsigned* u = reinterpret_cast<const unsigned*>(&r);
#pragma unroll
    for (int i = 0; i < 4; i++) {
        o[2*i]   = __uint_as_float(u[i] << 16);
        o[2*i+1] = __uint_as_float(u[i] & 0xffff0000u);
    }
}

// ---------------- K1: LN + projections (q,k,v,g) + tri_bias ----------------
__global__ __launch_bounds__(256) void k_proj(
    const float* __restrict__ x, const float* __restrict__ ln_g, const float* __restrict__ ln_b,
    const float* __restrict__ w_bias, const float* __restrict__ wq, const float* __restrict__ wk,
    const float* __restrict__ wvw, const float* __restrict__ wg, const float* __restrict__ bg,
    bf16* __restrict__ qo, bf16* __restrict__ ko, bf16* __restrict__ vo, bf16* __restrict__ go,
    float* __restrict__ tri)
{
    __shared__ float xst[CC][36];   // transposed: xst[c][pixel]
    const int t = threadIdx.x;
    const size_t pixbase = (size_t)blockIdx.x * 32;

    // load 32 pixels x 128 channels, transpose into LDS
    const float4* xsrc = reinterpret_cast<const float4*>(x + pixbase * CC);
#pragma unroll
    for (int r = 0; r < 4; r++) {
        int i4 = t + 256*r;
        float4 xv = xsrc[i4];
        int idx = i4*4;
        int p = idx >> 7, c = idx & 127;
        xst[c][p] = xv.x; xst[c+1][p] = xv.y; xst[c+2][p] = xv.z; xst[c+3][p] = xv.w;
    }
    __syncthreads();

    // LayerNorm: 8 threads per pixel
    {
        const int p = t >> 3, l = t & 7;
        float s = 0.f, s2 = 0.f;
#pragma unroll
        for (int c = l; c < CC; c += 8) { float v = xst[c][p]; s += v; s2 += v*v; }
#pragma unroll
        for (int off = 4; off > 0; off >>= 1) {
            s  += __shfl_down(s, off, 8);
            s2 += __shfl_down(s2, off, 8);
        }
        float mu   = __shfl(s, 0, 8) * (1.f/CC);
        float var  = __shfl(s2, 0, 8) * (1.f/CC) - mu*mu;
        float rstd = rsqrtf(var + 1e-5f);
#pragma unroll
        for (int c = l; c < CC; c += 8) {
            xst[c][p] = (xst[c][p] - mu) * rstd * ln_g[c] + ln_b[c];
        }
    }
    __syncthreads();

    // tri bias: 32 pixels x 4 heads
    if (t < 128) {
        int p = t >> 2, h = t & 3;
        float acc = 0.f;
        for (int c = 0; c < CC; c++) acc += xst[c][p] * w_bias[c*HH + h];
        tri[(size_t)h*NP + pixbase + p] = acc;
    }

    // projections: 4x4 register-blocked, 32 pixels x 128 cols per tile
    const int ox = (t & 31) * 4, py = (t >> 5) * 4;
    const float* Ws[4] = {wq, wk, wvw, wg};
    bf16* Os[4] = {qo, ko, vo, go};
#pragma unroll
    for (int m = 0; m < 4; m++) {
        const float* __restrict__ W = Ws[m];
        float acc[4][4];
#pragma unroll
        for (int u = 0; u < 4; u++)
#pragma unroll
            for (int v = 0; v < 4; v++) acc[u][v] = 0.f;
#pragma unroll 4
        for (int c = 0; c < CC; c++) {
            float4 w4 = *reinterpret_cast<const float4*>(&W[c*HC + ox]);
            float4 x4 = *reinterpret_cast<const float4*>(&xst[c][py]);
            float wc[4] = {w4.x, w4.y, w4.z, w4.w};
            float xp[4] = {x4.x, x4.y, x4.z, x4.w};
#pragma unroll
            for (int u = 0; u < 4; u++)
#pragma unroll
                for (int v = 0; v < 4; v++) acc[u][v] += xp[u] * wc[v];
        }
        if (m == 0) {
            const float qs = 0.17677669529663687f;  // 1/sqrt(32)
#pragma unroll
            for (int u = 0; u < 4; u++)
#pragma unroll
                for (int v = 0; v < 4; v++) acc[u][v] *= qs;
        }
        if (m == 3) {
            float4 b4 = *reinterpret_cast<const float4*>(&bg[ox]);
            float bgv[4] = {b4.x, b4.y, b4.z, b4.w};
#pragma unroll
            for (int u = 0; u < 4; u++)
#pragma unroll
                for (int v = 0; v < 4; v++) {
                    float z = acc[u][v] + bgv[v];
                    acc[u][v] = 1.f / (1.f + __expf(-z));
                }
        }
        bf16* O = Os[m];
#pragma unroll
        for (int u = 0; u < 4; u++) {
            store_bf16x4(O + (pixbase + py + u)*HC + ox,
                         acc[u][0], acc[u][1], acc[u][2], acc[u][3]);
        }
    }
}

// ---------------- K2: attention per (i, h, 16-query tile) ----------------
__global__ __launch_bounds__(256) void k_attn(
    const bf16* __restrict__ qi, const bf16* __restrict__ ki, const bf16* __restrict__ vi,
    const bf16* __restrict__ gi, const float* __restrict__ mask, const float* __restrict__ tri,
    bf16* __restrict__ oo)
{
    __shared__ float sc[16][324];    // scores, pad 324: float4-aligned, <=2-way banks
    __shared__ float red[16][17];
    __shared__ float rowmaxs[16];
    __shared__ float rowinv[16];
    __shared__ float pbuf[16][33];
    const int t = threadIdx.x;
    const int qt = blockIdx.x;       // 0..19
    const int h  = blockIdx.y;       // 0..3
    const int i  = blockIdx.z;       // 0..319
    const int qbase = qt * 16;
    const int qrow = t & 15;
    const int kk   = t >> 4;         // 0..15

    // q row into registers (already scaled in K1)
    float qreg[32];
    {
        const float4* q4 = reinterpret_cast<const float4*>(
            qi + ((size_t)(i*NN + qbase + qrow))*HC + h*CHD);
#pragma unroll
        for (int r = 0; r < 4; r++) unpack8(q4[r], &qreg[8*r]);
    }
    const size_t kvbase = ((size_t)i*NN)*HC + h*CHD;
    const float* maskrow = mask + (size_t)i*NN;
    const float* trirow  = tri + (size_t)h*NP + (size_t)(qbase + qrow)*NN;

    // pass 1: scores
#pragma unroll 1
    for (int m = 0; m < 20; m++) {
        int kcol = kk + (m << 4);
        const float4* k4 = reinterpret_cast<const float4*>(ki + kvbase + (size_t)kcol*HC);
        float s = 0.f;
#pragma unroll
        for (int r = 0; r < 4; r++) {
            float kf[8]; unpack8(k4[r], kf);
#pragma unroll
            for (int d = 0; d < 8; d++) s += qreg[8*r+d] * kf[d];
        }
        s += 1.0e9f * (maskrow[kcol] - 1.0f) + trirow[kcol];
        sc[qrow][kcol] = s;
    }
    __syncthreads();

    // softmax: per-row max
    {
        float pm = -3.0e38f;
#pragma unroll
        for (int m = 0; m < 20; m++) pm = fmaxf(pm, sc[qrow][kk + (m<<4)]);
        red[qrow][kk] = pm;
    }
    __syncthreads();
    if (t < 16) {
        float pm = red[t][0];
#pragma unroll
        for (int m2 = 1; m2 < 16; m2++) pm = fmaxf(pm, red[t][m2]);
        rowmaxs[t] = pm;
    }
    __syncthreads();
    {
        float rm = rowmaxs[qrow];
        float ps = 0.f;
#pragma unroll
        for (int m = 0; m < 20; m++) {
            int kcol = kk + (m<<4);
            float e = __expf(sc[qrow][kcol] - rm);
            sc[qrow][kcol] = e;
            ps += e;
        }
        red[qrow][kk] = ps;
    }
    __syncthreads();
    if (t < 16) {
        float ps = 0.f;
#pragma unroll
        for (int m2 = 0; m2 < 16; m2++) ps += red[t][m2];
        rowinv[t] = 1.f / ps;
    }
    __syncthreads();

    // pass 2: AV, split-K halves
    const int dq    = ((t >> 4) & 7) * 4;  // d quad base
    const int khalf = t >> 7;
    const int k0    = khalf * 160;
    float acc[4] = {0.f, 0.f, 0.f, 0.f};
#pragma unroll 1
    for (int kc = 0; kc < 160; kc += 4) {
        float4 p4v = *reinterpret_cast<const float4*>(&sc[qrow][k0 + kc]);
        float pp[4] = {p4v.x, p4v.y, p4v.z, p4v.w};
#pragma unroll
        for (int u = 0; u < 4; u++) {
            int kcol = k0 + kc + u;
            float2 v2 = *reinterpret_cast<const float2*>(vi + kvbase + (size_t)kcol*HC + dq);
            const unsigned* uu = reinterpret_cast<const unsigned*>(&v2);
            float vf0 = __uint_as_float(uu[0] << 16);
            float vf1 = __uint_as_float(uu[0] & 0xffff0000u);
            float vf2 = __uint_as_float(uu[1] << 16);
            float vf3 = __uint_as_float(uu[1] & 0xffff0000u);
            acc[0] += pp[u] * vf0;
            acc[1] += pp[u] * vf1;
            acc[2] += pp[u] * vf2;
            acc[3] += pp[u] * vf3;
        }
    }
    if (khalf == 1) {
#pragma unroll
        for (int w = 0; w < 4; w++) pbuf[qrow][dq + w] = acc[w];
    }
    __syncthreads();
    if (khalf == 0) {
        float inv = rowinv[qrow];
        size_t obase = ((size_t)(i*NN + qbase + qrow))*HC + h*CHD + dq;
        const bf16* gp = gi + obase;
        float r0 = (acc[0] + pbuf[qrow][dq+0]) * inv * bf2f(gp[0]);
        float r1 = (acc[1] + pbuf[qrow][dq+1]) * inv * bf2f(gp[1]);
        float r2 = (acc[2] + pbuf[qrow][dq+2]) * inv * bf2f(gp[2]);
        float r3 = (acc[3] + pbuf[qrow][dq+3]) * inv * bf2f(gp[3]);
        store_bf16x4(oo + obase, r0, r1, r2, r3);
    }
}

// ---------------- K3: output projection (fp32 output!) ----------------
__global__ __launch_bounds__(256) void k_out(
    const bf16* __restrict__ oi, const float* __restrict__ wo, const float* __restrict__ bo,
    float* __restrict__ outp)
{
    __shared__ float ost[HC][36];
    const int t = threadIdx.x;
    const size_t pixbase = (size_t)blockIdx.x * 32;
    const float4* osrc = reinterpret_cast<const float4*>(oi + pixbase*HC);
#pragma unroll
    for (int r = 0; r < 2; r++) {
        int i8 = t + 256*r;
        float f[8]; unpack8(osrc[i8], f);
        int idx = i8*8;
        int p = idx >> 7, c = idx & 127;
#pragma unroll
        for (int u = 0; u < 8; u++) ost[c+u][p] = f[u];
    }
    __syncthreads();
    const int cx = (t & 31)*4, py = (t >> 5)*4;
    float acc[4][4];
#pragma unroll
    for (int u = 0; u < 4; u++)
#pragma unroll
        for (int v = 0; v < 4; v++) acc[u][v] = 0.f;
#pragma unroll 4
    for (int d = 0; d < HC; d++) {
        float4 w4 = *reinterpret_cast<const float4*>(&wo[d*CC + cx]);
        float4 x4 = *reinterpret_cast<const float4*>(&ost[d][py]);
        float wc[4] = {w4.x, w4.y, w4.z, w4.w};
        float xp[4] = {x4.x, x4.y, x4.z, x4.w};
#pragma unroll
        for (int u = 0; u < 4; u++)
#pragma unroll
            for (int v = 0; v < 4; v++) acc[u][v] += xp[u] * wc[v];
    }
    float4 b4 = *reinterpret_cast<const float4*>(&bo[cx]);
#pragma unroll
    for (int u = 0; u < 4; u++) {
        float4 r;
        r.x = acc[u][0] + b4.x;
        r.y = acc[u][1] + b4.y;
        r.z = acc[u][2] + b4.z;
        r.w = acc[u][3] + b4.w;
        *reinterpret_cast<float4*>(outp + (pixbase + py + u)*CC + cx) = r;
    }
}

extern "C" void kernel_launch(void* const* d_in, const int* in_sizes, int n_in,
                              void* d_out, int out_size, void* d_ws, size_t ws_size,
                              hipStream_t stream) {
    const float* x      = (const float*)d_in[0];
    const float* mask   = (const float*)d_in[1];
    const float* ln_g   = (const float*)d_in[2];
    const float* ln_b   = (const float*)d_in[3];
    const float* w_bias = (const float*)d_in[4];
    const float* wq     = (const float*)d_in[5];
    const float* wk     = (const float*)d_in[6];
    const float* wv     = (const float*)d_in[7];
    const float* wg     = (const float*)d_in[8];
    const float* bg     = (const float*)d_in[9];
    const float* wo     = (const float*)d_in[10];
    const float* bo     = (const float*)d_in[11];
    float* outp = (float*)d_out;

    bf16* qws = (bf16*)d_ws;
    bf16* kws = qws + (size_t)NP*HC;
    bf16* vws = kws + (size_t)NP*HC;
    bf16* gws = vws + (size_t)NP*HC;
    bf16* ows = gws + (size_t)NP*HC;
    float* tri = (float*)(ows + (size_t)NP*HC);

    hipLaunchKernelGGL(k_proj, dim3(NP/32), dim3(256), 0, stream,
                       x, ln_g, ln_b, w_bias, wq, wk, wv, wg, bg,
                       qws, kws, vws, gws, tri);
    hipLaunchKernelGGL(k_attn, dim3(20, HH, NN), dim3(256), 0, stream,
                       qws, kws, vws, gws, mask, tri, ows);
    hipLaunchKernelGGL(k_out, dim3(NP/32), dim3(256), 0, stream,
                       ows, wo, bo, outp);
}

// Round 4
// 544.087 us; speedup vs baseline: 2.4512x; 2.4512x over previous
//
#include <hip/hip_runtime.h>
#include <hip/hip_bf16.h>

#define NN 320
#define CC 128
#define HH 4
#define CHD 32
#define HC 128
#define NP (NN*NN)

typedef __hip_bfloat16 bf16;
typedef __bf16 bfv8 __attribute__((ext_vector_type(8)));
typedef float fv4 __attribute__((ext_vector_type(4)));

__device__ __forceinline__ float bf2f(bf16 b) { return __bfloat162float(b); }

__device__ __forceinline__ unsigned short bfbits(float f) {
    bf16 h = __float2bfloat16(f);
    return *reinterpret_cast<unsigned short*>(&h);
}

__device__ __forceinline__ void store_bf16x4(bf16* p, float a, float b, float c, float d) {
    uint2 u;
    u.x = (unsigned)bfbits(a) | ((unsigned)bfbits(b) << 16);
    u.y = (unsigned)bfbits(c) | ((unsigned)bfbits(d) << 16);
    *reinterpret_cast<uint2*>(p) = u;
}

// unpack a float4-sized chunk holding 8 bf16 into 8 floats
__device__ __forceinline__ void unpack8(float4 r, float* o) {
    const unsigned* u = reinterpret_cast<const unsigned*>(&r);
#pragma unroll
    for (int i = 0; i < 4; i++) {
        o[2*i]   = __uint_as_float(u[i] << 16);
        o[2*i+1] = __uint_as_float(u[i] & 0xffff0000u);
    }
}

// ---------------- K1: LN + projections (q,k,v,g) + tri_bias ----------------
__global__ __launch_bounds__(256) void k_proj(
    const float* __restrict__ x, const float* __restrict__ ln_g, const float* __restrict__ ln_b,
    const float* __restrict__ w_bias, const float* __restrict__ wq, const float* __restrict__ wk,
    const float* __restrict__ wvw, const float* __restrict__ wg, const float* __restrict__ bg,
    bf16* __restrict__ qo, bf16* __restrict__ ko, bf16* __restrict__ vo, bf16* __restrict__ go,
    float* __restrict__ tri)
{
    __shared__ float xst[CC][36];   // transposed: xst[c][pixel]
    const int t = threadIdx.x;
    const size_t pixbase = (size_t)blockIdx.x * 32;

    const float4* xsrc = reinterpret_cast<const float4*>(x + pixbase * CC);
#pragma unroll
    for (int r = 0; r < 4; r++) {
        int i4 = t + 256*r;
        float4 xv = xsrc[i4];
        int idx = i4*4;
        int p = idx >> 7, c = idx & 127;
        xst[c][p] = xv.x; xst[c+1][p] = xv.y; xst[c+2][p] = xv.z; xst[c+3][p] = xv.w;
    }
    __syncthreads();

    {
        const int p = t >> 3, l = t & 7;
        float s = 0.f, s2 = 0.f;
#pragma unroll
        for (int c = l; c < CC; c += 8) { float v = xst[c][p]; s += v; s2 += v*v; }
#pragma unroll
        for (int off = 4; off > 0; off >>= 1) {
            s  += __shfl_down(s, off, 8);
            s2 += __shfl_down(s2, off, 8);
        }
        float mu   = __shfl(s, 0, 8) * (1.f/CC);
        float var  = __shfl(s2, 0, 8) * (1.f/CC) - mu*mu;
        float rstd = rsqrtf(var + 1e-5f);
#pragma unroll
        for (int c = l; c < CC; c += 8) {
            xst[c][p] = (xst[c][p] - mu) * rstd * ln_g[c] + ln_b[c];
        }
    }
    __syncthreads();

    if (t < 128) {
        int p = t >> 2, h = t & 3;
        float acc = 0.f;
        for (int c = 0; c < CC; c++) acc += xst[c][p] * w_bias[c*HH + h];
        tri[(size_t)h*NP + pixbase + p] = acc;
    }

    const int ox = (t & 31) * 4, py = (t >> 5) * 4;
    const float* Ws[4] = {wq, wk, wvw, wg};
    bf16* Os[4] = {qo, ko, vo, go};
#pragma unroll
    for (int m = 0; m < 4; m++) {
        const float* __restrict__ W = Ws[m];
        float acc[4][4];
#pragma unroll
        for (int u = 0; u < 4; u++)
#pragma unroll
            for (int v = 0; v < 4; v++) acc[u][v] = 0.f;
#pragma unroll 4
        for (int c = 0; c < CC; c++) {
            float4 w4 = *reinterpret_cast<const float4*>(&W[c*HC + ox]);
            float4 x4 = *reinterpret_cast<const float4*>(&xst[c][py]);
            float wc[4] = {w4.x, w4.y, w4.z, w4.w};
            float xp[4] = {x4.x, x4.y, x4.z, x4.w};
#pragma unroll
            for (int u = 0; u < 4; u++)
#pragma unroll
                for (int v = 0; v < 4; v++) acc[u][v] += xp[u] * wc[v];
        }
        if (m == 0) {
            const float qs = 0.17677669529663687f;  // 1/sqrt(32)
#pragma unroll
            for (int u = 0; u < 4; u++)
#pragma unroll
                for (int v = 0; v < 4; v++) acc[u][v] *= qs;
        }
        if (m == 3) {
            float4 b4 = *reinterpret_cast<const float4*>(&bg[ox]);
            float bgv[4] = {b4.x, b4.y, b4.z, b4.w};
#pragma unroll
            for (int u = 0; u < 4; u++)
#pragma unroll
                for (int v = 0; v < 4; v++) {
                    float z = acc[u][v] + bgv[v];
                    acc[u][v] = 1.f / (1.f + __expf(-z));
                }
        }
        bf16* O = Os[m];
#pragma unroll
        for (int u = 0; u < 4; u++) {
            store_bf16x4(O + (pixbase + py + u)*HC + ox,
                         acc[u][0], acc[u][1], acc[u][2], acc[u][3]);
        }
    }
}

// ---------------- K2: MFMA attention ----------------
// Per wave: 16 queries of one (i,h). S^T via mfma (A=K, B=Q), softmax over
// rows(=keys) with 2 shuffles, P packed to LDS [q][k], O^T via mfma
// (A=Vt staged in LDS, B=P).
__global__ __launch_bounds__(256) void k_attn(
    const bf16* __restrict__ qi, const bf16* __restrict__ ki, const bf16* __restrict__ vi,
    const bf16* __restrict__ gi, const float* __restrict__ mask, const float* __restrict__ tri,
    bf16* __restrict__ oo)
{
    __shared__ unsigned short Vt[32][328];      // Vt[dim][key], pad 328
    __shared__ unsigned short P[4][16][328];    // per-wave P[q][k] bf16

    const int t = threadIdx.x;
    const int w = t >> 6, lane = t & 63, g = lane >> 4, c = lane & 15;
    const int h = blockIdx.y, i = blockIdx.z;
    const int qb = blockIdx.x * 64 + w * 16;
    const size_t rowbase = (size_t)i * NN;

    // ---- stage Vt (transposed V head-slice) ----
#pragma unroll
    for (int it = 0; it < 5; it++) {
        int ci = it * 256 + t;         // 1280 chunks of 8 bf16
        int key = ci >> 2, d0 = (ci & 3) * 8;
        uint4 vv = *reinterpret_cast<const uint4*>(vi + (rowbase + key) * HC + h * CHD + d0);
        unsigned wd[4] = {vv.x, vv.y, vv.z, vv.w};
#pragma unroll
        for (int u = 0; u < 4; u++) {
            Vt[d0 + 2*u][key]     = (unsigned short)(wd[u] & 0xffffu);
            Vt[d0 + 2*u + 1][key] = (unsigned short)(wd[u] >> 16);
        }
    }

    // ---- Q B-fragment: B[k=d][n=q] = Q[qb+c][8g+j] ----
    bfv8 bq = *reinterpret_cast<const bfv8*>(qi + (rowbase + qb + c) * HC + h * CHD + 8 * g);

    const float* maskrow = mask + (size_t)i * NN;
    const float* trirow  = tri + (size_t)h * NP + (size_t)(qb + c) * NN;
    fv4 zero = {0.f, 0.f, 0.f, 0.f};

    // ---- pass 1: S^T tiles, lane holds rows(keys) kt*16+4g+r, col q=c ----
    float s[20][4];
#pragma unroll
    for (int kt = 0; kt < 20; kt++) {
        int kbase = kt * 16;
        bfv8 ak = *reinterpret_cast<const bfv8*>(ki + (rowbase + kbase + c) * HC + h * CHD + 8 * g);
        fv4 sa = __builtin_amdgcn_mfma_f32_16x16x32_bf16(ak, bq, zero, 0, 0, 0);
        float4 mk = *reinterpret_cast<const float4*>(maskrow + kbase + 4 * g);
        float4 tr = *reinterpret_cast<const float4*>(trirow + kbase + 4 * g);
        float mks[4] = {mk.x, mk.y, mk.z, mk.w};
        float trs[4] = {tr.x, tr.y, tr.z, tr.w};
#pragma unroll
        for (int r = 0; r < 4; r++) {
            float bias = 1.0e9f * (mks[r] - 1.0f);   // exact 0 when mask==1
            s[kt][r] = sa[r] + trs[r] + bias;
        }
    }

    // ---- softmax over keys (tiles x regs lane-local, then g-groups) ----
    float mx = -3.0e38f;
#pragma unroll
    for (int kt = 0; kt < 20; kt++)
#pragma unroll
        for (int r = 0; r < 4; r++) mx = fmaxf(mx, s[kt][r]);
    mx = fmaxf(mx, __shfl_xor(mx, 16, 64));
    mx = fmaxf(mx, __shfl_xor(mx, 32, 64));
    float sm = 0.f;
#pragma unroll
    for (int kt = 0; kt < 20; kt++)
#pragma unroll
        for (int r = 0; r < 4; r++) {
            float e = __expf(s[kt][r] - mx);
            s[kt][r] = e;
            sm += e;
        }
    sm += __shfl_xor(sm, 16, 64);
    sm += __shfl_xor(sm, 32, 64);
    float linv = 1.f / sm;

    // ---- write P[q=c][k] as bf16, 4 consecutive k per lane (8B packed) ----
#pragma unroll
    for (int kt = 0; kt < 20; kt++) {
        uint2 pk;
        pk.x = (unsigned)bfbits(s[kt][0]) | ((unsigned)bfbits(s[kt][1]) << 16);
        pk.y = (unsigned)bfbits(s[kt][2]) | ((unsigned)bfbits(s[kt][3]) << 16);
        *reinterpret_cast<uint2*>(&P[w][c][kt * 16 + 4 * g]) = pk;
    }
    __syncthreads();

    // ---- pass 2: O^T = Vt @ P^T, M=32 dims (2 tiles), K=320 ----
    fv4 o0 = zero, o1 = zero;
#pragma unroll
    for (int ks = 0; ks < 10; ks++) {
        bfv8 bp  = *reinterpret_cast<const bfv8*>(&P[w][c][ks * 32 + 8 * g]);
        bfv8 av0 = *reinterpret_cast<const bfv8*>(&Vt[c][ks * 32 + 8 * g]);
        bfv8 av1 = *reinterpret_cast<const bfv8*>(&Vt[16 + c][ks * 32 + 8 * g]);
        o0 = __builtin_amdgcn_mfma_f32_16x16x32_bf16(av0, bp, o0, 0, 0, 0);
        o1 = __builtin_amdgcn_mfma_f32_16x16x32_bf16(av1, bp, o1, 0, 0, 0);
    }

    // ---- epilogue: scale by 1/l (in-register, q=c matches), gate, store ----
    size_t obase = (rowbase + qb + c) * HC + h * CHD;
#pragma unroll
    for (int mt = 0; mt < 2; mt++) {
        fv4 oc = mt ? o1 : o0;
        int d0 = mt * 16 + 4 * g;      // 4 consecutive dims per lane
        uint2 gg = *reinterpret_cast<const uint2*>(gi + obase + d0);
        float gf0 = __uint_as_float(gg.x << 16);
        float gf1 = __uint_as_float(gg.x & 0xffff0000u);
        float gf2 = __uint_as_float(gg.y << 16);
        float gf3 = __uint_as_float(gg.y & 0xffff0000u);
        uint2 st;
        st.x = (unsigned)bfbits(oc[0] * linv * gf0) | ((unsigned)bfbits(oc[1] * linv * gf1) << 16);
        st.y = (unsigned)bfbits(oc[2] * linv * gf2) | ((unsigned)bfbits(oc[3] * linv * gf3) << 16);
        *reinterpret_cast<uint2*>(oo + obase + d0) = st;
    }
}

// ---------------- K3: output projection (fp32 output) ----------------
__global__ __launch_bounds__(256) void k_out(
    const bf16* __restrict__ oi, const float* __restrict__ wo, const float* __restrict__ bo,
    float* __restrict__ outp)
{
    __shared__ float ost[HC][36];
    const int t = threadIdx.x;
    const size_t pixbase = (size_t)blockIdx.x * 32;
    const float4* osrc = reinterpret_cast<const float4*>(oi + pixbase*HC);
#pragma unroll
    for (int r = 0; r < 2; r++) {
        int i8 = t + 256*r;
        float f[8]; unpack8(osrc[i8], f);
        int idx = i8*8;
        int p = idx >> 7, c = idx & 127;
#pragma unroll
        for (int u = 0; u < 8; u++) ost[c+u][p] = f[u];
    }
    __syncthreads();
    const int cx = (t & 31)*4, py = (t >> 5)*4;
    float acc[4][4];
#pragma unroll
    for (int u = 0; u < 4; u++)
#pragma unroll
        for (int v = 0; v < 4; v++) acc[u][v] = 0.f;
#pragma unroll 4
    for (int d = 0; d < HC; d++) {
        float4 w4 = *reinterpret_cast<const float4*>(&wo[d*CC + cx]);
        float4 x4 = *reinterpret_cast<const float4*>(&ost[d][py]);
        float wc[4] = {w4.x, w4.y, w4.z, w4.w};
        float xp[4] = {x4.x, x4.y, x4.z, x4.w};
#pragma unroll
        for (int u = 0; u < 4; u++)
#pragma unroll
            for (int v = 0; v < 4; v++) acc[u][v] += xp[u] * wc[v];
    }
    float4 b4 = *reinterpret_cast<const float4*>(&bo[cx]);
#pragma unroll
    for (int u = 0; u < 4; u++) {
        float4 r;
        r.x = acc[u][0] + b4.x;
        r.y = acc[u][1] + b4.y;
        r.z = acc[u][2] + b4.z;
        r.w = acc[u][3] + b4.w;
        *reinterpret_cast<float4*>(outp + (pixbase + py + u)*CC + cx) = r;
    }
}

extern "C" void kernel_launch(void* const* d_in, const int* in_sizes, int n_in,
                              void* d_out, int out_size, void* d_ws, size_t ws_size,
                              hipStream_t stream) {
    const float* x      = (const float*)d_in[0];
    const float* mask   = (const float*)d_in[1];
    const float* ln_g   = (const float*)d_in[2];
    const float* ln_b   = (const float*)d_in[3];
    const float* w_bias = (const float*)d_in[4];
    const float* wq     = (const float*)d_in[5];
    const float* wk     = (const float*)d_in[6];
    const float* wv     = (const float*)d_in[7];
    const float* wg     = (const float*)d_in[8];
    const float* bg     = (const float*)d_in[9];
    const float* wo     = (const float*)d_in[10];
    const float* bo     = (const float*)d_in[11];
    float* outp = (float*)d_out;

    bf16* qws = (bf16*)d_ws;
    bf16* kws = qws + (size_t)NP*HC;
    bf16* vws = kws + (size_t)NP*HC;
    bf16* gws = vws + (size_t)NP*HC;
    bf16* ows = gws + (size_t)NP*HC;
    float* tri = (float*)(ows + (size_t)NP*HC);

    hipLaunchKernelGGL(k_proj, dim3(NP/32), dim3(256), 0, stream,
                       x, ln_g, ln_b, w_bias, wq, wk, wv, wg, bg,
                       qws, kws, vws, gws, tri);
    hipLaunchKernelGGL(k_attn, dim3(5, HH, NN), dim3(256), 0, stream,
                       qws, kws, vws, gws, mask, tri, ows);
    hipLaunchKernelGGL(k_out, dim3(NP/32), dim3(256), 0, stream,
                       ows, wo, bo, outp);
}

// Round 5
// 434.842 us; speedup vs baseline: 3.0670x; 1.2512x over previous
//
#include <hip/hip_runtime.h>
#include <hip/hip_bf16.h>

#define NN 320
#define CC 128
#define HH 4
#define CHD 32
#define HC 128
#define NP (NN*NN)

typedef __hip_bfloat16 bf16;
typedef __bf16 bfv8 __attribute__((ext_vector_type(8)));
typedef float fv4 __attribute__((ext_vector_type(4)));

__device__ __forceinline__ unsigned short bfbits(float f) {
    bf16 h = __float2bfloat16(f);
    return *reinterpret_cast<unsigned short*>(&h);
}

// ---------------- K0: weight convert/transpose to bf16 ----------------
// wt[m][out][c] (m: q,k,v,g; q pre-scaled by 1/sqrt(32)), wot[out_c][d],
// wtb[16][c] (rows 0..3 = w_bias^T, rows 4..15 zero)
__global__ __launch_bounds__(256) void k_wconv(
    const float* __restrict__ wq, const float* __restrict__ wk,
    const float* __restrict__ wv, const float* __restrict__ wg,
    const float* __restrict__ wo, const float* __restrict__ w_bias,
    bf16* __restrict__ wt, bf16* __restrict__ wot, bf16* __restrict__ wtb)
{
    __shared__ unsigned short T[128 * 136];
    const int b = blockIdx.x, t = threadIdx.x;
    if (b < 5) {
        const float* W = (b == 0) ? wq : (b == 1) ? wk : (b == 2) ? wv : (b == 3) ? wg : wo;
        bf16* D = (b < 4) ? (wt + b * 16384) : wot;
        const float scale = (b == 0) ? 0.17677669529663687f : 1.0f;
        for (int idx = t; idx < 16384; idx += 256) {
            int c = idx >> 7, out = idx & 127;
            T[out * 136 + c] = bfbits(W[idx] * scale);   // coalesced read, LDS transpose
        }
        __syncthreads();
        for (int i8 = t; i8 < 2048; i8 += 256) {
            int out = i8 >> 4, c0 = (i8 & 15) * 8;
            uint4 v = *reinterpret_cast<const uint4*>(&T[out * 136 + c0]);
            *reinterpret_cast<uint4*>(D + out * 128 + c0) = v;   // coalesced write
        }
    } else {
        int out = t >> 4, c0 = (t & 15) * 8;
        unsigned short vals[8];
#pragma unroll
        for (int j = 0; j < 8; j++)
            vals[j] = (out < 4) ? bfbits(w_bias[(c0 + j) * 4 + out]) : (unsigned short)0;
        *reinterpret_cast<uint4*>(wtb + out * 128 + c0) = *reinterpret_cast<uint4*>(vals);
    }
}

// ---------------- K1: LN + MFMA projections + tri_bias ----------------
__global__ __launch_bounds__(256) void k_proj(
    const float* __restrict__ x, const float* __restrict__ ln_g, const float* __restrict__ ln_b,
    const bf16* __restrict__ wt, const bf16* __restrict__ wtb, const float* __restrict__ bg,
    bf16* __restrict__ qo, bf16* __restrict__ ko, bf16* __restrict__ vo, bf16* __restrict__ go,
    float* __restrict__ tri)
{
    __shared__ unsigned short A[64 * 136];    // LN(x) bf16, [pixel][c], pad 8
    __shared__ unsigned short Bn[64 * 136];   // store bounce
    const int t = threadIdx.x;
    const int wv = t >> 6, lane = t & 63, g = lane >> 4, c = lane & 15;
    const size_t pb = (size_t)blockIdx.x * 64;

    // ---- LayerNorm in registers: 4 threads per pixel ----
    {
        const int p = t >> 2, l = t & 3;
        const float* xr = x + (pb + p) * CC + l * 32;
        float4 xv[8];
#pragma unroll
        for (int i = 0; i < 8; i++) xv[i] = reinterpret_cast<const float4*>(xr)[i];
        float s = 0.f, s2 = 0.f;
#pragma unroll
        for (int i = 0; i < 8; i++) {
            s  += xv[i].x + xv[i].y + xv[i].z + xv[i].w;
            s2 += xv[i].x * xv[i].x + xv[i].y * xv[i].y + xv[i].z * xv[i].z + xv[i].w * xv[i].w;
        }
        s  += __shfl_xor(s, 1, 4);  s  += __shfl_xor(s, 2, 4);
        s2 += __shfl_xor(s2, 1, 4); s2 += __shfl_xor(s2, 2, 4);
        float mu = s * (1.f / CC);
        float var = s2 * (1.f / CC) - mu * mu;
        float rstd = rsqrtf(var + 1e-5f);
        const float4* gr = reinterpret_cast<const float4*>(ln_g + l * 32);
        const float4* br = reinterpret_cast<const float4*>(ln_b + l * 32);
#pragma unroll
        for (int i = 0; i < 8; i += 2) {
            float4 g0 = gr[i], g1 = gr[i + 1], b0 = br[i], b1 = br[i + 1];
            uint4 pk;
            pk.x = (unsigned)bfbits((xv[i].x - mu) * rstd * g0.x + b0.x)
                 | ((unsigned)bfbits((xv[i].y - mu) * rstd * g0.y + b0.y) << 16);
            pk.y = (unsigned)bfbits((xv[i].z - mu) * rstd * g0.z + b0.z)
                 | ((unsigned)bfbits((xv[i].w - mu) * rstd * g0.w + b0.w) << 16);
            pk.z = (unsigned)bfbits((xv[i+1].x - mu) * rstd * g1.x + b1.x)
                 | ((unsigned)bfbits((xv[i+1].y - mu) * rstd * g1.y + b1.y) << 16);
            pk.w = (unsigned)bfbits((xv[i+1].z - mu) * rstd * g1.z + b1.z)
                 | ((unsigned)bfbits((xv[i+1].w - mu) * rstd * g1.w + b1.w) << 16);
            *reinterpret_cast<uint4*>(&A[p * 136 + l * 32 + i * 4]) = pk;
        }
    }
    __syncthreads();

    // ---- A-fragments (shared across all 5 matmuls) ----
    bfv8 af[4];
#pragma unroll
    for (int kc = 0; kc < 4; kc++)
        af[kc] = *reinterpret_cast<const bfv8*>(&A[(wv * 16 + c) * 136 + kc * 32 + 8 * g]);

    fv4 zero = {0.f, 0.f, 0.f, 0.f};

    // ---- tri bias: one MFMA tile against padded w_bias^T ----
    {
        fv4 at = zero;
#pragma unroll
        for (int kc = 0; kc < 4; kc++) {
            bfv8 bb = *reinterpret_cast<const bfv8*>(wtb + c * 128 + kc * 32 + 8 * g);
            at = __builtin_amdgcn_mfma_f32_16x16x32_bf16(af[kc], bb, at, 0, 0, 0);
        }
        if (c < HH) {
            float4 st = {at[0], at[1], at[2], at[3]};   // 4 consecutive pixels
            *reinterpret_cast<float4*>(tri + (size_t)c * NP + pb + wv * 16 + 4 * g) = st;
        }
    }

    // ---- q,k,v,g projections ----
    bf16* Os[4] = {qo, ko, vo, go};
#pragma unroll 1
    for (int m = 0; m < 4; m++) {
        const bf16* WtM = wt + m * 16384;
        fv4 acc[8];
#pragma unroll
        for (int n = 0; n < 8; n++) acc[n] = zero;
#pragma unroll
        for (int n = 0; n < 8; n++)
#pragma unroll
            for (int kc = 0; kc < 4; kc++) {
                bfv8 bb = *reinterpret_cast<const bfv8*>(WtM + (n * 16 + c) * 128 + kc * 32 + 8 * g);
                acc[n] = __builtin_amdgcn_mfma_f32_16x16x32_bf16(af[kc], bb, acc[n], 0, 0, 0);
            }
        if (m == 3) {
#pragma unroll
            for (int n = 0; n < 8; n++) {
                float bgv = bg[n * 16 + c];
#pragma unroll
                for (int r = 0; r < 4; r++) {
                    float z = acc[n][r] + bgv;
                    acc[n][r] = 1.f / (1.f + __expf(-z));
                }
            }
        }
        // bounce (wave-private rows -> no barrier) then coalesced 16B stores
#pragma unroll
        for (int n = 0; n < 8; n++)
#pragma unroll
            for (int r = 0; r < 4; r++)
                Bn[(wv * 16 + 4 * g + r) * 136 + n * 16 + c] = bfbits(acc[n][r]);
        int row = wv * 16 + (lane >> 2), c0 = (lane & 3) * 32;
        bf16* O = Os[m];
#pragma unroll
        for (int j = 0; j < 4; j++) {
            uint4 v = *reinterpret_cast<const uint4*>(&Bn[row * 136 + c0 + 8 * j]);
            *reinterpret_cast<uint4*>(O + (pb + row) * HC + c0 + 8 * j) = v;
        }
    }
}

// ---------------- K2: MFMA attention (unchanged from R4) ----------------
__global__ __launch_bounds__(256) void k_attn(
    const bf16* __restrict__ qi, const bf16* __restrict__ ki, const bf16* __restrict__ vi,
    const bf16* __restrict__ gi, const float* __restrict__ mask, const float* __restrict__ tri,
    bf16* __restrict__ oo)
{
    __shared__ unsigned short Vt[32][328];
    __shared__ unsigned short P[4][16][328];

    const int t = threadIdx.x;
    const int w = t >> 6, lane = t & 63, g = lane >> 4, c = lane & 15;
    const int h = blockIdx.y, i = blockIdx.z;
    const int qb = blockIdx.x * 64 + w * 16;
    const size_t rowbase = (size_t)i * NN;

#pragma unroll
    for (int it = 0; it < 5; it++) {
        int ci = it * 256 + t;
        int key = ci >> 2, d0 = (ci & 3) * 8;
        uint4 vv = *reinterpret_cast<const uint4*>(vi + (rowbase + key) * HC + h * CHD + d0);
        unsigned wd[4] = {vv.x, vv.y, vv.z, vv.w};
#pragma unroll
        for (int u = 0; u < 4; u++) {
            Vt[d0 + 2*u][key]     = (unsigned short)(wd[u] & 0xffffu);
            Vt[d0 + 2*u + 1][key] = (unsigned short)(wd[u] >> 16);
        }
    }

    bfv8 bq = *reinterpret_cast<const bfv8*>(qi + (rowbase + qb + c) * HC + h * CHD + 8 * g);

    const float* maskrow = mask + (size_t)i * NN;
    const float* trirow  = tri + (size_t)h * NP + (size_t)(qb + c) * NN;
    fv4 zero = {0.f, 0.f, 0.f, 0.f};

    float s[20][4];
#pragma unroll
    for (int kt = 0; kt < 20; kt++) {
        int kbase = kt * 16;
        bfv8 ak = *reinterpret_cast<const bfv8*>(ki + (rowbase + kbase + c) * HC + h * CHD + 8 * g);
        fv4 sa = __builtin_amdgcn_mfma_f32_16x16x32_bf16(ak, bq, zero, 0, 0, 0);
        float4 mk = *reinterpret_cast<const float4*>(maskrow + kbase + 4 * g);
        float4 tr = *reinterpret_cast<const float4*>(trirow + kbase + 4 * g);
        float mks[4] = {mk.x, mk.y, mk.z, mk.w};
        float trs[4] = {tr.x, tr.y, tr.z, tr.w};
#pragma unroll
        for (int r = 0; r < 4; r++) {
            float bias = 1.0e9f * (mks[r] - 1.0f);
            s[kt][r] = sa[r] + trs[r] + bias;
        }
    }

    float mx = -3.0e38f;
#pragma unroll
    for (int kt = 0; kt < 20; kt++)
#pragma unroll
        for (int r = 0; r < 4; r++) mx = fmaxf(mx, s[kt][r]);
    mx = fmaxf(mx, __shfl_xor(mx, 16, 64));
    mx = fmaxf(mx, __shfl_xor(mx, 32, 64));
    float sm = 0.f;
#pragma unroll
    for (int kt = 0; kt < 20; kt++)
#pragma unroll
        for (int r = 0; r < 4; r++) {
            float e = __expf(s[kt][r] - mx);
            s[kt][r] = e;
            sm += e;
        }
    sm += __shfl_xor(sm, 16, 64);
    sm += __shfl_xor(sm, 32, 64);
    float linv = 1.f / sm;

#pragma unroll
    for (int kt = 0; kt < 20; kt++) {
        uint2 pk;
        pk.x = (unsigned)bfbits(s[kt][0]) | ((unsigned)bfbits(s[kt][1]) << 16);
        pk.y = (unsigned)bfbits(s[kt][2]) | ((unsigned)bfbits(s[kt][3]) << 16);
        *reinterpret_cast<uint2*>(&P[w][c][kt * 16 + 4 * g]) = pk;
    }
    __syncthreads();

    fv4 o0 = zero, o1 = zero;
#pragma unroll
    for (int ks = 0; ks < 10; ks++) {
        bfv8 bp  = *reinterpret_cast<const bfv8*>(&P[w][c][ks * 32 + 8 * g]);
        bfv8 av0 = *reinterpret_cast<const bfv8*>(&Vt[c][ks * 32 + 8 * g]);
        bfv8 av1 = *reinterpret_cast<const bfv8*>(&Vt[16 + c][ks * 32 + 8 * g]);
        o0 = __builtin_amdgcn_mfma_f32_16x16x32_bf16(av0, bp, o0, 0, 0, 0);
        o1 = __builtin_amdgcn_mfma_f32_16x16x32_bf16(av1, bp, o1, 0, 0, 0);
    }

    size_t obase = (rowbase + qb + c) * HC + h * CHD;
#pragma unroll
    for (int mt = 0; mt < 2; mt++) {
        fv4 oc = mt ? o1 : o0;
        int d0 = mt * 16 + 4 * g;
        uint2 gg = *reinterpret_cast<const uint2*>(gi + obase + d0);
        float gf0 = __uint_as_float(gg.x << 16);
        float gf1 = __uint_as_float(gg.x & 0xffff0000u);
        float gf2 = __uint_as_float(gg.y << 16);
        float gf3 = __uint_as_float(gg.y & 0xffff0000u);
        uint2 st;
        st.x = (unsigned)bfbits(oc[0] * linv * gf0) | ((unsigned)bfbits(oc[1] * linv * gf1) << 16);
        st.y = (unsigned)bfbits(oc[2] * linv * gf2) | ((unsigned)bfbits(oc[3] * linv * gf3) << 16);
        *reinterpret_cast<uint2*>(oo + obase + d0) = st;
    }
}

// ---------------- K3: MFMA output projection (fp32 out) ----------------
__global__ __launch_bounds__(256) void k_out(
    const bf16* __restrict__ oi, const bf16* __restrict__ wot, const float* __restrict__ bo,
    float* __restrict__ outp)
{
    const int t = threadIdx.x;
    const int wv = t >> 6, lane = t & 63, g = lane >> 4, c = lane & 15;
    const size_t pb = (size_t)blockIdx.x * 64;

    bfv8 af[4];
#pragma unroll
    for (int kc = 0; kc < 4; kc++)
        af[kc] = *reinterpret_cast<const bfv8*>(oi + (pb + wv * 16 + c) * HC + kc * 32 + 8 * g);

    fv4 zero = {0.f, 0.f, 0.f, 0.f};
    fv4 acc[8];
#pragma unroll
    for (int n = 0; n < 8; n++) acc[n] = zero;
#pragma unroll
    for (int n = 0; n < 8; n++)
#pragma unroll
        for (int kc = 0; kc < 4; kc++) {
            bfv8 bb = *reinterpret_cast<const bfv8*>(wot + (n * 16 + c) * 128 + kc * 32 + 8 * g);
            acc[n] = __builtin_amdgcn_mfma_f32_16x16x32_bf16(af[kc], bb, acc[n], 0, 0, 0);
        }
#pragma unroll
    for (int n = 0; n < 8; n++) {
        float bov = bo[n * 16 + c];
#pragma unroll
        for (int r = 0; r < 4; r++)
            outp[(pb + wv * 16 + 4 * g + r) * CC + n * 16 + c] = acc[n][r] + bov;
    }
}

extern "C" void kernel_launch(void* const* d_in, const int* in_sizes, int n_in,
                              void* d_out, int out_size, void* d_ws, size_t ws_size,
                              hipStream_t stream) {
    const float* x      = (const float*)d_in[0];
    const float* mask   = (const float*)d_in[1];
    const float* ln_g   = (const float*)d_in[2];
    const float* ln_b   = (const float*)d_in[3];
    const float* w_bias = (const float*)d_in[4];
    const float* wq     = (const float*)d_in[5];
    const float* wk     = (const float*)d_in[6];
    const float* wv     = (const float*)d_in[7];
    const float* wg     = (const float*)d_in[8];
    const float* bg     = (const float*)d_in[9];
    const float* wo     = (const float*)d_in[10];
    const float* bo     = (const float*)d_in[11];
    float* outp = (float*)d_out;

    bf16* qws = (bf16*)d_ws;
    bf16* kws = qws + (size_t)NP*HC;
    bf16* vws = kws + (size_t)NP*HC;
    bf16* gws = vws + (size_t)NP*HC;
    bf16* ows = gws + (size_t)NP*HC;
    float* tri = (float*)(ows + (size_t)NP*HC);
    bf16* wt  = (bf16*)(tri + (size_t)NP*HH);
    bf16* wot = wt + 4 * 16384;
    bf16* wtb = wot + 16384;

    hipLaunchKernelGGL(k_wconv, dim3(6), dim3(256), 0, stream,
                       wq, wk, wv, wg, wo, w_bias, wt, wot, wtb);
    hipLaunchKernelGGL(k_proj, dim3(NP/64), dim3(256), 0, stream,
                       x, ln_g, ln_b, wt, wtb, bg, qws, kws, vws, gws, tri);
    hipLaunchKernelGGL(k_attn, dim3(5, HH, NN), dim3(256), 0, stream,
                       qws, kws, vws, gws, mask, tri, ows);
    hipLaunchKernelGGL(k_out, dim3(NP/64), dim3(256), 0, stream,
                       ows, wot, bo, outp);
}

// Round 6
// 392.971 us; speedup vs baseline: 3.3938x; 1.1065x over previous
//
#include <hip/hip_runtime.h>
#include <hip/hip_bf16.h>

#define NN 320
#define CC 128
#define HH 4
#define CHD 32
#define HC 128
#define NP (NN*NN)

typedef __hip_bfloat16 bf16;
typedef __bf16 bfv8 __attribute__((ext_vector_type(8)));
typedef float fv4 __attribute__((ext_vector_type(4)));

__device__ __forceinline__ unsigned short bfbits(float f) {
    bf16 h = __float2bfloat16(f);
    return *reinterpret_cast<unsigned short*>(&h);
}

// ---------------- K0: weight convert/transpose to bf16 ----------------
__global__ __launch_bounds__(256) void k_wconv(
    const float* __restrict__ wq, const float* __restrict__ wk,
    const float* __restrict__ wv, const float* __restrict__ wg,
    const float* __restrict__ wo, const float* __restrict__ w_bias,
    bf16* __restrict__ wt, bf16* __restrict__ wot, bf16* __restrict__ wtb)
{
    __shared__ unsigned short T[128 * 136];
    const int b = blockIdx.x, t = threadIdx.x;
    if (b < 5) {
        const float* W = (b == 0) ? wq : (b == 1) ? wk : (b == 2) ? wv : (b == 3) ? wg : wo;
        bf16* D = (b < 4) ? (wt + b * 16384) : wot;
        const float scale = (b == 0) ? 0.17677669529663687f : 1.0f;
        for (int idx = t; idx < 16384; idx += 256) {
            int c = idx >> 7, out = idx & 127;
            T[out * 136 + c] = bfbits(W[idx] * scale);
        }
        __syncthreads();
        for (int i8 = t; i8 < 2048; i8 += 256) {
            int out = i8 >> 4, c0 = (i8 & 15) * 8;
            uint4 v = *reinterpret_cast<const uint4*>(&T[out * 136 + c0]);
            *reinterpret_cast<uint4*>(D + out * 128 + c0) = v;
        }
    } else {
        int out = t >> 4, c0 = (t & 15) * 8;
        unsigned short vals[8];
#pragma unroll
        for (int j = 0; j < 8; j++)
            vals[j] = (out < 4) ? bfbits(w_bias[(c0 + j) * 4 + out]) : (unsigned short)0;
        *reinterpret_cast<uint4*>(wtb + out * 128 + c0) = *reinterpret_cast<uint4*>(vals);
    }
}

// ---------------- K1: LN + MFMA projections + tri_bias ----------------
// A = weight frag (out-channels on D-rows), B = pixel frag -> packed 8B stores,
// no LDS bounce. 2 pixel tiles per wave (weight frag reused 2x).
__global__ __launch_bounds__(256) void k_proj(
    const float* __restrict__ x, const float* __restrict__ ln_g, const float* __restrict__ ln_b,
    const bf16* __restrict__ wt, const bf16* __restrict__ wtb, const float* __restrict__ bg,
    bf16* __restrict__ qo, bf16* __restrict__ ko, bf16* __restrict__ vo, bf16* __restrict__ go,
    float* __restrict__ tri)
{
    __shared__ unsigned short A[128 * 136];   // LN(x) bf16, [pixel][c], pad 8
    const int t = threadIdx.x;
    const int wv = t >> 6, lane = t & 63, g = lane >> 4, c = lane & 15;
    const size_t pb = (size_t)blockIdx.x * 128;

    // ---- LayerNorm in registers: 4 threads per pixel, 2 rounds ----
#pragma unroll
    for (int rnd = 0; rnd < 2; rnd++) {
        const int p = (t >> 2) + rnd * 64, l = t & 3;
        const float* xr = x + (pb + p) * CC + l * 32;
        float4 xv[8];
#pragma unroll
        for (int i = 0; i < 8; i++) xv[i] = reinterpret_cast<const float4*>(xr)[i];
        float s = 0.f, s2 = 0.f;
#pragma unroll
        for (int i = 0; i < 8; i++) {
            s  += xv[i].x + xv[i].y + xv[i].z + xv[i].w;
            s2 += xv[i].x * xv[i].x + xv[i].y * xv[i].y + xv[i].z * xv[i].z + xv[i].w * xv[i].w;
        }
        s  += __shfl_xor(s, 1, 4);  s  += __shfl_xor(s, 2, 4);
        s2 += __shfl_xor(s2, 1, 4); s2 += __shfl_xor(s2, 2, 4);
        float mu = s * (1.f / CC);
        float var = s2 * (1.f / CC) - mu * mu;
        float rstd = rsqrtf(var + 1e-5f);
        const float4* gr = reinterpret_cast<const float4*>(ln_g + l * 32);
        const float4* br = reinterpret_cast<const float4*>(ln_b + l * 32);
#pragma unroll
        for (int i = 0; i < 8; i += 2) {
            float4 g0 = gr[i], g1 = gr[i + 1], b0 = br[i], b1 = br[i + 1];
            uint4 pk;
            pk.x = (unsigned)bfbits((xv[i].x - mu) * rstd * g0.x + b0.x)
                 | ((unsigned)bfbits((xv[i].y - mu) * rstd * g0.y + b0.y) << 16);
            pk.y = (unsigned)bfbits((xv[i].z - mu) * rstd * g0.z + b0.z)
                 | ((unsigned)bfbits((xv[i].w - mu) * rstd * g0.w + b0.w) << 16);
            pk.z = (unsigned)bfbits((xv[i+1].x - mu) * rstd * g1.x + b1.x)
                 | ((unsigned)bfbits((xv[i+1].y - mu) * rstd * g1.y + b1.y) << 16);
            pk.w = (unsigned)bfbits((xv[i+1].z - mu) * rstd * g1.z + b1.z)
                 | ((unsigned)bfbits((xv[i+1].w - mu) * rstd * g1.w + b1.w) << 16);
            *reinterpret_cast<uint4*>(&A[p * 136 + l * 32 + i * 4]) = pk;
        }
    }
    __syncthreads();

    // ---- pixel fragments: 2 tiles of 16 pixels per wave ----
    // layout serves as A-frag (m=pixel) for tri AND B-frag (n=pixel) for proj
    bfv8 bx[2][4];
#pragma unroll
    for (int tile = 0; tile < 2; tile++)
#pragma unroll
        for (int kc = 0; kc < 4; kc++)
            bx[tile][kc] = *reinterpret_cast<const bfv8*>(
                &A[(wv * 32 + tile * 16 + c) * 136 + kc * 32 + 8 * g]);

    fv4 zero = {0.f, 0.f, 0.f, 0.f};

    // ---- tri bias: A=pixels, B=w_bias^T (D col = head) ----
    {
        fv4 at0 = zero, at1 = zero;
#pragma unroll
        for (int kc = 0; kc < 4; kc++) {
            bfv8 bb = *reinterpret_cast<const bfv8*>(wtb + c * 128 + kc * 32 + 8 * g);
            at0 = __builtin_amdgcn_mfma_f32_16x16x32_bf16(bx[0][kc], bb, at0, 0, 0, 0);
            at1 = __builtin_amdgcn_mfma_f32_16x16x32_bf16(bx[1][kc], bb, at1, 0, 0, 0);
        }
        if (c < HH) {
            float4 s0 = {at0[0], at0[1], at0[2], at0[3]};
            float4 s1 = {at1[0], at1[1], at1[2], at1[3]};
            float* tb = tri + (size_t)c * NP + pb + wv * 32 + 4 * g;
            *reinterpret_cast<float4*>(tb)      = s0;
            *reinterpret_cast<float4*>(tb + 16) = s1;
        }
    }

    // ---- q,k,v,g projections: A=weights, B=pixels ----
    bf16* Os[4] = {qo, ko, vo, go};
#pragma unroll 1
    for (int m = 0; m < 4; m++) {
        const bf16* WtM = wt + m * 16384;
        fv4 acc[2][8];
#pragma unroll
        for (int n = 0; n < 8; n++) { acc[0][n] = zero; acc[1][n] = zero; }
#pragma unroll
        for (int n = 0; n < 8; n++)
#pragma unroll
            for (int kc = 0; kc < 4; kc++) {
                bfv8 bw = *reinterpret_cast<const bfv8*>(WtM + (n * 16 + c) * 128 + kc * 32 + 8 * g);
                acc[0][n] = __builtin_amdgcn_mfma_f32_16x16x32_bf16(bw, bx[0][kc], acc[0][n], 0, 0, 0);
                acc[1][n] = __builtin_amdgcn_mfma_f32_16x16x32_bf16(bw, bx[1][kc], acc[1][n], 0, 0, 0);
            }
        if (m == 3) {
#pragma unroll
            for (int n = 0; n < 8; n++) {
                float4 bgv = *reinterpret_cast<const float4*>(bg + n * 16 + 4 * g);
                float bgs[4] = {bgv.x, bgv.y, bgv.z, bgv.w};
#pragma unroll
                for (int tile = 0; tile < 2; tile++)
#pragma unroll
                    for (int r = 0; r < 4; r++) {
                        float z = acc[tile][n][r] + bgs[r];
                        acc[tile][n][r] = 1.f / (1.f + __expf(-z));
                    }
            }
        }
        bf16* O = Os[m];
#pragma unroll
        for (int tile = 0; tile < 2; tile++)
#pragma unroll
            for (int n = 0; n < 8; n++) {
                uint2 pk;
                pk.x = (unsigned)bfbits(acc[tile][n][0]) | ((unsigned)bfbits(acc[tile][n][1]) << 16);
                pk.y = (unsigned)bfbits(acc[tile][n][2]) | ((unsigned)bfbits(acc[tile][n][3]) << 16);
                *reinterpret_cast<uint2*>(O + (pb + wv * 32 + tile * 16 + c) * HC + n * 16 + 4 * g) = pk;
            }
    }
}

// ---------------- K2: MFMA attention (unchanged) ----------------
__global__ __launch_bounds__(256) void k_attn(
    const bf16* __restrict__ qi, const bf16* __restrict__ ki, const bf16* __restrict__ vi,
    const bf16* __restrict__ gi, const float* __restrict__ mask, const float* __restrict__ tri,
    bf16* __restrict__ oo)
{
    __shared__ unsigned short Vt[32][328];
    __shared__ unsigned short P[4][16][328];

    const int t = threadIdx.x;
    const int w = t >> 6, lane = t & 63, g = lane >> 4, c = lane & 15;
    const int h = blockIdx.y, i = blockIdx.z;
    const int qb = blockIdx.x * 64 + w * 16;
    const size_t rowbase = (size_t)i * NN;

#pragma unroll
    for (int it = 0; it < 5; it++) {
        int ci = it * 256 + t;
        int key = ci >> 2, d0 = (ci & 3) * 8;
        uint4 vv = *reinterpret_cast<const uint4*>(vi + (rowbase + key) * HC + h * CHD + d0);
        unsigned wd[4] = {vv.x, vv.y, vv.z, vv.w};
#pragma unroll
        for (int u = 0; u < 4; u++) {
            Vt[d0 + 2*u][key]     = (unsigned short)(wd[u] & 0xffffu);
            Vt[d0 + 2*u + 1][key] = (unsigned short)(wd[u] >> 16);
        }
    }

    bfv8 bq = *reinterpret_cast<const bfv8*>(qi + (rowbase + qb + c) * HC + h * CHD + 8 * g);

    const float* maskrow = mask + (size_t)i * NN;
    const float* trirow  = tri + (size_t)h * NP + (size_t)(qb + c) * NN;
    fv4 zero = {0.f, 0.f, 0.f, 0.f};

    float s[20][4];
#pragma unroll
    for (int kt = 0; kt < 20; kt++) {
        int kbase = kt * 16;
        bfv8 ak = *reinterpret_cast<const bfv8*>(ki + (rowbase + kbase + c) * HC + h * CHD + 8 * g);
        fv4 sa = __builtin_amdgcn_mfma_f32_16x16x32_bf16(ak, bq, zero, 0, 0, 0);
        float4 mk = *reinterpret_cast<const float4*>(maskrow + kbase + 4 * g);
        float4 tr = *reinterpret_cast<const float4*>(trirow + kbase + 4 * g);
        float mks[4] = {mk.x, mk.y, mk.z, mk.w};
        float trs[4] = {tr.x, tr.y, tr.z, tr.w};
#pragma unroll
        for (int r = 0; r < 4; r++) {
            float bias = 1.0e9f * (mks[r] - 1.0f);
            s[kt][r] = sa[r] + trs[r] + bias;
        }
    }

    float mx = -3.0e38f;
#pragma unroll
    for (int kt = 0; kt < 20; kt++)
#pragma unroll
        for (int r = 0; r < 4; r++) mx = fmaxf(mx, s[kt][r]);
    mx = fmaxf(mx, __shfl_xor(mx, 16, 64));
    mx = fmaxf(mx, __shfl_xor(mx, 32, 64));
    float sm = 0.f;
#pragma unroll
    for (int kt = 0; kt < 20; kt++)
#pragma unroll
        for (int r = 0; r < 4; r++) {
            float e = __expf(s[kt][r] - mx);
            s[kt][r] = e;
            sm += e;
        }
    sm += __shfl_xor(sm, 16, 64);
    sm += __shfl_xor(sm, 32, 64);
    float linv = 1.f / sm;

#pragma unroll
    for (int kt = 0; kt < 20; kt++) {
        uint2 pk;
        pk.x = (unsigned)bfbits(s[kt][0]) | ((unsigned)bfbits(s[kt][1]) << 16);
        pk.y = (unsigned)bfbits(s[kt][2]) | ((unsigned)bfbits(s[kt][3]) << 16);
        *reinterpret_cast<uint2*>(&P[w][c][kt * 16 + 4 * g]) = pk;
    }
    __syncthreads();

    fv4 o0 = zero, o1 = zero;
#pragma unroll
    for (int ks = 0; ks < 10; ks++) {
        bfv8 bp  = *reinterpret_cast<const bfv8*>(&P[w][c][ks * 32 + 8 * g]);
        bfv8 av0 = *reinterpret_cast<const bfv8*>(&Vt[c][ks * 32 + 8 * g]);
        bfv8 av1 = *reinterpret_cast<const bfv8*>(&Vt[16 + c][ks * 32 + 8 * g]);
        o0 = __builtin_amdgcn_mfma_f32_16x16x32_bf16(av0, bp, o0, 0, 0, 0);
        o1 = __builtin_amdgcn_mfma_f32_16x16x32_bf16(av1, bp, o1, 0, 0, 0);
    }

    size_t obase = (rowbase + qb + c) * HC + h * CHD;
#pragma unroll
    for (int mt = 0; mt < 2; mt++) {
        fv4 oc = mt ? o1 : o0;
        int d0 = mt * 16 + 4 * g;
        uint2 gg = *reinterpret_cast<const uint2*>(gi + obase + d0);
        float gf0 = __uint_as_float(gg.x << 16);
        float gf1 = __uint_as_float(gg.x & 0xffff0000u);
        float gf2 = __uint_as_float(gg.y << 16);
        float gf3 = __uint_as_float(gg.y & 0xffff0000u);
        uint2 st;
        st.x = (unsigned)bfbits(oc[0] * linv * gf0) | ((unsigned)bfbits(oc[1] * linv * gf1) << 16);
        st.y = (unsigned)bfbits(oc[2] * linv * gf2) | ((unsigned)bfbits(oc[3] * linv * gf3) << 16);
        *reinterpret_cast<uint2*>(oo + obase + d0) = st;
    }
}

// ---------------- K3: MFMA output projection (fp32 out, float4 stores) ----------------
__global__ __launch_bounds__(256) void k_out(
    const bf16* __restrict__ oi, const bf16* __restrict__ wot, const float* __restrict__ bo,
    float* __restrict__ outp)
{
    const int t = threadIdx.x;
    const int wv = t >> 6, lane = t & 63, g = lane >> 4, c = lane & 15;
    const size_t pb = (size_t)blockIdx.x * 64;

    bfv8 bx[4];
#pragma unroll
    for (int kc = 0; kc < 4; kc++)
        bx[kc] = *reinterpret_cast<const bfv8*>(oi + (pb + wv * 16 + c) * HC + kc * 32 + 8 * g);

    fv4 zero = {0.f, 0.f, 0.f, 0.f};
    fv4 acc[8];
#pragma unroll
    for (int n = 0; n < 8; n++) acc[n] = zero;
#pragma unroll
    for (int n = 0; n < 8; n++)
#pragma unroll
        for (int kc = 0; kc < 4; kc++) {
            bfv8 bw = *reinterpret_cast<const bfv8*>(wot + (n * 16 + c) * 128 + kc * 32 + 8 * g);
            acc[n] = __builtin_amdgcn_mfma_f32_16x16x32_bf16(bw, bx[kc], acc[n], 0, 0, 0);
        }
#pragma unroll
    for (int n = 0; n < 8; n++) {
        float4 b4 = *reinterpret_cast<const float4*>(bo + n * 16 + 4 * g);
        float4 st;
        st.x = acc[n][0] + b4.x;
        st.y = acc[n][1] + b4.y;
        st.z = acc[n][2] + b4.z;
        st.w = acc[n][3] + b4.w;
        *reinterpret_cast<float4*>(outp + (pb + wv * 16 + c) * CC + n * 16 + 4 * g) = st;
    }
}

extern "C" void kernel_launch(void* const* d_in, const int* in_sizes, int n_in,
                              void* d_out, int out_size, void* d_ws, size_t ws_size,
                              hipStream_t stream) {
    const float* x      = (const float*)d_in[0];
    const float* mask   = (const float*)d_in[1];
    const float* ln_g   = (const float*)d_in[2];
    const float* ln_b   = (const float*)d_in[3];
    const float* w_bias = (const float*)d_in[4];
    const float* wq     = (const float*)d_in[5];
    const float* wk     = (const float*)d_in[6];
    const float* wv     = (const float*)d_in[7];
    const float* wg     = (const float*)d_in[8];
    const float* bg     = (const float*)d_in[9];
    const float* wo     = (const float*)d_in[10];
    const float* bo     = (const float*)d_in[11];
    float* outp = (float*)d_out;

    bf16* qws = (bf16*)d_ws;
    bf16* kws = qws + (size_t)NP*HC;
    bf16* vws = kws + (size_t)NP*HC;
    bf16* gws = vws + (size_t)NP*HC;
    bf16* ows = gws + (size_t)NP*HC;
    float* tri = (float*)(ows + (size_t)NP*HC);
    bf16* wt  = (bf16*)(tri + (size_t)NP*HH);
    bf16* wot = wt + 4 * 16384;
    bf16* wtb = wot + 16384;

    hipLaunchKernelGGL(k_wconv, dim3(6), dim3(256), 0, stream,
                       wq, wk, wv, wg, wo, w_bias, wt, wot, wtb);
    hipLaunchKernelGGL(k_proj, dim3(NP/128), dim3(256), 0, stream,
                       x, ln_g, ln_b, wt, wtb, bg, qws, kws, vws, gws, tri);
    hipLaunchKernelGGL(k_attn, dim3(5, HH, NN), dim3(256), 0, stream,
                       qws, kws, vws, gws, mask, tri, ows);
    hipLaunchKernelGGL(k_out, dim3(NP/64), dim3(256), 0, stream,
                       ows, wot, bo, outp);
}